// Round 11
// baseline (262.485 us; speedup 1.0000x reference)
//
#include <hip/hip_runtime.h>
#include <hip/hip_bf16.h>

#define BB 8
#define NN 2048
#define DD 128
#define TI 16
#define HP 132
#define CH 32
#define NC (NN / CH)   // 64
#define NO (NC + 1)    // 65
#define GRID 256
#define TPB 256

__device__ __forceinline__ float relu(float x) { return x > 0.f ? x : 0.f; }

// Device-scope grid barrier. Safe because GRID=256 blocks of 256 thr / <=45KB
// LDS guarantee 1 resident block per CU (256 CUs). Counters zeroed by
// hipMemsetAsync before launch; one counter per phase (no reset races).
__device__ __forceinline__ void gridbar(unsigned* bar, int p) {
    __syncthreads();
    if (threadIdx.x == 0) {
        __threadfence();   // publish this block's global writes device-wide
        __hip_atomic_fetch_add(&bar[p], 1u, __ATOMIC_ACQ_REL, __HIP_MEMORY_SCOPE_AGENT);
        while (__hip_atomic_load(&bar[p], __ATOMIC_ACQUIRE, __HIP_MEMORY_SCOPE_AGENT) < GRID)
            __builtin_amdgcn_s_sleep(1);
        __threadfence();
    }
    __syncthreads();
}

__global__ __launch_bounds__(TPB, 1) void GraphAttentionalLayer_1168231104632_mega(
    const float* __restrict__ h,
    const float* __restrict__ W,
    const float* __restrict__ a,
    float* __restrict__ out,
    float* __restrict__ WT,  float* __restrict__ hw,
    float* __restrict__ E,   float* __restrict__ F,
    float* __restrict__ Fs,  float* __restrict__ FPL,
    float* __restrict__ CF,  float* __restrict__ OF,
    int* __restrict__ perm,
    float* __restrict__ Q0L, float* __restrict__ Q1L,
    float* __restrict__ C0,  float* __restrict__ C1,
    float* __restrict__ O0,  float* __restrict__ O1,
    unsigned* __restrict__ bar)
{
    __shared__ float h_s[2][TI][HP];     // 16.9 KB
    __shared__ float wt_s[32][HP];       // 16.9 KB
    __shared__ float F_s[NN];            // 8 KB
    __shared__ int   part[4][64];        // 1 KB
    __shared__ float T0s[DD], T1s[DD];   // 1 KB
    __shared__ int   k_sh[64];
    __shared__ float e_sh[64], zi_sh[64];

    const int tid = threadIdx.x;
    const int half = tid >> 7;           // 0/1
    const int t = tid & 127;

    // ================= P0: WT[d][e] = W[e][d] =================
    {
        const int g = blockIdx.x * TPB + tid;
        if (g < DD * DD) {
            const int d = g >> 7, e = g & 127;
            WT[g] = W[e * DD + d];
        }
    }
    gridbar(bar, 0);

    // ================= P1: hw = h@W^T ; E=exp(si), F=exp(sj) =================
    // Two 16-row tiles in parallel (one per half-block); r9-verified inner loop.
    {
        const int tx = t & 31, ty = t >> 5;
        const int e0 = tx * 4, r0 = ty * 4;
        for (int it = 0; it < 2; it++) {
            const int tile = blockIdx.x * 4 + it * 2 + half;   // 0..1023
            const int bb = tile >> 7;
            const int i0 = (tile & 127) * TI;
            const size_t base = ((size_t)bb * NN + i0) * DD;

            __syncthreads();   // protect h_s from previous iteration's readers
            for (int r = 0; r < TI; r++)
                h_s[half][r][t] = h[base + (size_t)r * DD + t];

            float acc[4][4];
#pragma unroll
            for (int i = 0; i < 4; i++)
#pragma unroll
                for (int j = 0; j < 4; j++) acc[i][j] = 0.f;

            for (int dc = 0; dc < DD; dc += 32) {
                __syncthreads();
                for (int rr = half; rr < 32; rr += 2)
                    wt_s[rr][t] = WT[(size_t)(dc + rr) * DD + t];
                __syncthreads();
#pragma unroll 4
                for (int dd = 0; dd < 32; dd++) {
                    const float4 wv = *reinterpret_cast<const float4*>(&wt_s[dd][e0]);
                    const float w4[4] = {wv.x, wv.y, wv.z, wv.w};
#pragma unroll
                    for (int r = 0; r < 4; r++) {
                        const float hv = h_s[half][r0 + r][dc + dd];
#pragma unroll
                        for (int e = 0; e < 4; e++) acc[r][e] += hv * w4[e];
                    }
                }
            }

#pragma unroll
            for (int r = 0; r < 4; r++) {
                float4 o = make_float4(acc[r][0], acc[r][1], acc[r][2], acc[r][3]);
                *reinterpret_cast<float4*>(&hw[base + (size_t)(r0 + r) * DD + e0]) = o;
            }

            const float4 aiv = *reinterpret_cast<const float4*>(&a[e0]);
            const float4 ajv = *reinterpret_cast<const float4*>(&a[DD + e0]);
            const float ai4[4] = {aiv.x, aiv.y, aiv.z, aiv.w};
            const float aj4[4] = {ajv.x, ajv.y, ajv.z, ajv.w};
#pragma unroll
            for (int r = 0; r < 4; r++) {
                float pi = 0.f, pj = 0.f;
#pragma unroll
                for (int e = 0; e < 4; e++) { pi += acc[r][e] * ai4[e]; pj += acc[r][e] * aj4[e]; }
#pragma unroll
                for (int off = 16; off > 0; off >>= 1) {
                    pi += __shfl_down(pi, off, 32);
                    pj += __shfl_down(pj, off, 32);
                }
                if (tx == 0) {
                    const size_t row = (size_t)bb * NN + i0 + r0 + r;
                    E[row] = __expf(pi);
                    F[row] = __expf(pj);
                }
            }
        }
    }
    gridbar(bar, 1);

    // ================= P2: rank-sort (r9 verbatim; grid shape matches) =================
    {
        const int b = blockIdx.x >> 5;
        const int j0 = (blockIdx.x & 31) * 64;
        const size_t nb = (size_t)b * NN;

        for (int q = 0; q < NN / TPB; q++)
            F_s[q * TPB + tid] = F[nb + q * TPB + tid];
        __syncthreads();

        const int tj = tid & 63, ts = tid >> 6;
        const int j = j0 + tj;
        const float fj = F_s[j];
        const int m0 = ts * (NN / 4);
        int cnt = 0;
#pragma unroll 8
        for (int mi = 0; mi < NN / 4; mi++) {
            const int m = m0 + mi;
            const float fm = F_s[m];
            cnt += (fm < fj) | ((fm == fj) & (m < j));
        }
        part[ts][tj] = cnt;
        __syncthreads();
        if (ts == 0) {
            const int r = part[0][tj] + part[1][tj] + part[2][tj] + part[3][tj];
            Fs[nb + r] = fj;
            perm[nb + r] = j;
        }
    }
    gridbar(bar, 2);

    // ================= P3: chunked scans (2 chunks per block) =================
    {
        const int chunk = blockIdx.x * 2 + half;   // 0..511
        const int b = chunk / NC, c = chunk % NC;
        const size_t nb = (size_t)b * NN;
        const int m0 = c * CH;

        int   jv[CH];
        float Fv[CH];
#pragma unroll
        for (int mm = 0; mm < CH; mm++) jv[mm] = perm[nb + m0 + mm];
#pragma unroll
        for (int mm = 0; mm < CH; mm++) Fv[mm] = Fs[nb + m0 + mm];

        float hv[CH];
#pragma unroll
        for (int mm = 0; mm < CH; mm++)
            hv[mm] = hw[(nb + jv[mm]) * DD + t];

        float a0 = 0.f, a1 = 0.f;
#pragma unroll
        for (int mm = 0; mm < CH; mm++) {
            const int m = m0 + mm;
            Q0L[(nb + m) * DD + t] = a0;
            Q1L[(nb + m) * DD + t] = a1;
            a0 += hv[mm];
            a1 += Fv[mm] * hv[mm];
        }
        C0[((size_t)b * NC + c) * DD + t] = a0;
        C1[((size_t)b * NC + c) * DD + t] = a1;

        if (t == 0) {
            float p = 0.f;
#pragma unroll
            for (int mm = 0; mm < CH; mm++) {
                FPL[nb + m0 + mm] = p;
                p += Fv[mm];
            }
            CF[(size_t)b * NC + c] = p;
        }
    }
    gridbar(bar, 3);

    // ================= P4: chunk-offset fixup (1024 parallel columns) =================
    {
        const int g = blockIdx.x * TPB + tid;
        if (g < BB * DD) {                 // 1024 columns (b,d)
            const int b = g >> 7, d = g & 127;
            float o0 = 0.f, o1 = 0.f;
            for (int cc = 0; cc < NC; cc += 16) {
                float c0[16], c1[16];
#pragma unroll
                for (int q = 0; q < 16; q++) {
                    c0[q] = C0[((size_t)b * NC + cc + q) * DD + d];
                    c1[q] = C1[((size_t)b * NC + cc + q) * DD + d];
                }
#pragma unroll
                for (int q = 0; q < 16; q++) {
                    O0[((size_t)b * NO + cc + q) * DD + d] = o0;
                    O1[((size_t)b * NO + cc + q) * DD + d] = o1;
                    o0 += c0[q];
                    o1 += c1[q];
                }
            }
            O0[((size_t)b * NO + NC) * DD + d] = o0;
            O1[((size_t)b * NO + NC) * DD + d] = o1;
        } else if (g < BB * DD + BB) {     // 8 threads: OF scan of CF
            const int b = g - BB * DD;
            float p = 0.f;
            for (int c = 0; c < NC; c++) {
                OF[(size_t)b * NO + c] = p;
                p += CF[(size_t)b * NC + c];
            }
            OF[(size_t)b * NO + NC] = p;
        }
    }
    gridbar(bar, 4);

    // ================= P5: output (64 rows per block) =================
    {
        const int row0 = blockIdx.x * 64;
        const int b = row0 >> 11;
        const size_t nb = (size_t)b * NN;

        if (tid < DD) {
            T0s[tid] = O0[((size_t)b * NO + NC) * DD + tid];
            T1s[tid] = O1[((size_t)b * NO + NC) * DD + tid];
        }
        if (tid < 64) {
            const int row = row0 + tid;
            const float Ei = E[row];
            const float thr = 1.0f / Ei;
            int lo = 0, hi = NN;
            while (lo < hi) {
                const int mid = (lo + hi) >> 1;
                if (Fs[nb + mid] < thr) lo = mid + 1; else hi = mid;
            }
            const float TF = OF[(size_t)b * NO + NC];
            const float Pk = (lo < NN) ? (OF[(size_t)b * NO + (lo >> 5)] + FPL[nb + lo]) : TF;
            const float z = Ei * (TF - Pk) + (float)lo;
            k_sh[tid] = lo; e_sh[tid] = Ei; zi_sh[tid] = 1.0f / z;
        }
        __syncthreads();

        for (int it = 0; it < 32; it++) {
            const int idx = it * 2 + half;
            const int k = k_sh[idx];
            const float Ev = e_sh[idx], zv = zi_sh[idx];
            float num;
            if (k < NN) {
                const int c = k >> 5;
                const float q0 = Q0L[(nb + k) * DD + t] + O0[((size_t)b * NO + c) * DD + t];
                const float q1 = Q1L[(nb + k) * DD + t] + O1[((size_t)b * NO + c) * DD + t];
                num = Ev * (T1s[t] - q1) + q0;
            } else {
                num = T0s[t];
            }
            out[(size_t)(row0 + idx) * DD + t] = relu(num * zv);
        }
    }
}

extern "C" __attribute__((visibility("default")))
void kernel_launch(void* const* d_in, const int* in_sizes, int n_in,
                   void* d_out, int out_size, void* d_ws, size_t ws_size,
                   hipStream_t stream) {
    const float* h = nullptr; const float* W = nullptr; const float* a = nullptr;
    for (int i = 0; i < n_in; i++) {
        if (in_sizes[i] == BB * NN * DD)      h = (const float*)d_in[i];
        else if (in_sizes[i] == DD * DD)      W = (const float*)d_in[i];
        else if (in_sizes[i] == 2 * DD)       a = (const float*)d_in[i];
    }
    if (!h) h = (const float*)d_in[0];
    if (!W) W = (const float*)d_in[1];
    if (!a) a = (const float*)d_in[2];

    float* out = (float*)d_out;
    float* ws = (float*)d_ws;

    float* WT   = ws;                              // 16,384
    float* hw   = WT + DD * DD;                    // 2,097,152
    float* E    = hw + (size_t)BB * NN * DD;       // 16,384
    float* F    = E + BB * NN;                     // 16,384
    float* Fs   = F + BB * NN;                     // 16,384
    float* FPL  = Fs + BB * NN;                    // 16,384
    float* CF   = FPL + BB * NN;                   // 512
    float* OF   = CF + BB * NC;                    // 520
    int*   perm = (int*)(OF + BB * NO);            // 16,384
    float* Q0L  = (float*)(perm + BB * NN);        // 2,097,152
    float* Q1L  = Q0L + (size_t)BB * NN * DD;      // 2,097,152
    float* C0   = Q1L + (size_t)BB * NN * DD;      // 65,536
    float* C1   = C0 + BB * NC * DD;               // 65,536
    float* O0   = C1 + BB * NC * DD;               // 66,560
    float* O1   = O0 + BB * NO * DD;               // 66,560
    unsigned* bar = (unsigned*)(O1 + BB * NO * DD);// 16 (pad 64B)
    const size_t need = ((char*)(bar + 16) - (char*)ws);   // ~26.7 MB

    if (ws_size < need || d_ws == nullptr) {
        hipMemsetAsync(d_out, 0x42, (size_t)out_size * sizeof(float), stream);
        return;
    }

    hipMemsetAsync(bar, 0, 64, stream);
    GraphAttentionalLayer_1168231104632_mega<<<GRID, TPB, 0, stream>>>(
        h, W, a, out,
        WT, hw, E, F, Fs, FPL, CF, OF, perm,
        Q0L, Q1L, C0, C1, O0, O1, bar);
}

// Round 12
// 126.613 us; speedup vs baseline: 2.0731x; 2.0731x over previous
//
#include <hip/hip_runtime.h>
#include <hip/hip_bf16.h>

#define BB 8
#define NN 2048
#define DD 128
#define TI 16     // i-rows per block (hw GEMM)
#define HP 132    // padded row stride for 128-wide LDS tiles
#define CH 32     // scan chunk length
#define NC (NN / CH)   // 64 chunks per batch
#define NO (NC + 1)    // 65 offset rows (incl. grand total)
#define NG 4           // 16-chunk groups per batch

__device__ __forceinline__ float relu(float x) { return x > 0.f ? x : 0.f; }

// ---------- Kernel 0: WT[d][e] = W[e][d] ----------
__global__ __launch_bounds__(256) void GraphAttentionalLayer_1168231104632_tr(
    const float* __restrict__ W, float* __restrict__ WT)
{
    const int g = blockIdx.x * 256 + threadIdx.x;
    const int d = g >> 7, e = g & 127;
    WT[g] = W[e * DD + d];
}

// ---------- Kernel 1: hw = h@W^T ; E=exp(si), F=exp(sj) ---------- (r9 verbatim)
__global__ __launch_bounds__(128) void GraphAttentionalLayer_1168231104632_kernel(
    const float* __restrict__ h,
    const float* __restrict__ WT,
    const float* __restrict__ a,
    float* __restrict__ hw,
    float* __restrict__ E,
    float* __restrict__ F)
{
    __shared__ float h_s[TI][HP];
    __shared__ float wt_s[32][HP];

    const int t = threadIdx.x;
    const int tx = t & 31, ty = t >> 5;
    const int b = blockIdx.x >> 7;
    const int i0 = (blockIdx.x & 127) * TI;
    const size_t base = ((size_t)b * NN + i0) * DD;

    for (int r = 0; r < TI; r++)
        h_s[r][t] = h[base + (size_t)r * DD + t];

    const int e0 = tx * 4, r0 = ty * 4;
    float acc[4][4];
#pragma unroll
    for (int i = 0; i < 4; i++)
#pragma unroll
        for (int j = 0; j < 4; j++) acc[i][j] = 0.f;

    for (int dc = 0; dc < DD; dc += 32) {
        __syncthreads();
        for (int rr = 0; rr < 32; rr++)
            wt_s[rr][t] = WT[(size_t)(dc + rr) * DD + t];
        __syncthreads();
#pragma unroll 4
        for (int dd = 0; dd < 32; dd++) {
            const float4 wv = *reinterpret_cast<const float4*>(&wt_s[dd][e0]);
            const float w4[4] = {wv.x, wv.y, wv.z, wv.w};
#pragma unroll
            for (int r = 0; r < 4; r++) {
                const float hv = h_s[r0 + r][dc + dd];
#pragma unroll
                for (int e = 0; e < 4; e++) acc[r][e] += hv * w4[e];
            }
        }
    }

#pragma unroll
    for (int r = 0; r < 4; r++) {
        float4 o = make_float4(acc[r][0], acc[r][1], acc[r][2], acc[r][3]);
        *reinterpret_cast<float4*>(&hw[base + (size_t)(r0 + r) * DD + e0]) = o;
    }

    const float4 aiv = *reinterpret_cast<const float4*>(&a[e0]);
    const float4 ajv = *reinterpret_cast<const float4*>(&a[DD + e0]);
    const float ai4[4] = {aiv.x, aiv.y, aiv.z, aiv.w};
    const float aj4[4] = {ajv.x, ajv.y, ajv.z, ajv.w};
#pragma unroll
    for (int r = 0; r < 4; r++) {
        float pi = 0.f, pj = 0.f;
#pragma unroll
        for (int e = 0; e < 4; e++) { pi += acc[r][e] * ai4[e]; pj += acc[r][e] * aj4[e]; }
#pragma unroll
        for (int off = 16; off > 0; off >>= 1) {
            pi += __shfl_down(pi, off, 32);
            pj += __shfl_down(pj, off, 32);
        }
        if (tx == 0) {
            const size_t row = (size_t)b * NN + i0 + r0 + r;
            E[row] = __expf(pi);
            F[row] = __expf(pj);
        }
    }
}

// ---------- Kernel 2: rank-sort, cooperative (r9 verbatim) ----------
__global__ __launch_bounds__(256) void GraphAttentionalLayer_1168231104632_rank(
    const float* __restrict__ F,
    float* __restrict__ Fsorted,
    int* __restrict__ perm)
{
    __shared__ float F_s[NN];
    __shared__ int   part[4][64];

    const int t = threadIdx.x;
    const int b = blockIdx.x >> 5;
    const int j0 = (blockIdx.x & 31) * 64;
    const size_t nb = (size_t)b * NN;

    for (int q = 0; q < NN / 256; q++)
        F_s[q * 256 + t] = F[nb + q * 256 + t];
    __syncthreads();

    const int tj = t & 63, ts = t >> 6;
    const int j = j0 + tj;
    const float fj = F_s[j];
    const int m0 = ts * (NN / 4);
    int cnt = 0;
#pragma unroll 8
    for (int mi = 0; mi < NN / 4; mi++) {
        const int m = m0 + mi;
        const float fm = F_s[m];
        cnt += (fm < fj) | ((fm == fj) & (m < j));
    }
    part[ts][tj] = cnt;
    __syncthreads();
    if (ts == 0) {
        const int r = part[0][tj] + part[1][tj] + part[2][tj] + part[3][tj];
        Fsorted[nb + r] = fj;
        perm[nb + r] = j;
    }
}

// ---------- Kernel 3: chunked scans + F-prefix metadata (r10 verbatim) ----------
__global__ __launch_bounds__(128) void GraphAttentionalLayer_1168231104632_scan(
    const float* __restrict__ hw,
    const float* __restrict__ Fsorted,
    const int* __restrict__ perm,
    float* __restrict__ Q0L, float* __restrict__ Q1L,
    float* __restrict__ C0,  float* __restrict__ C1,
    float* __restrict__ FPL, float* __restrict__ CF)
{
    const int t = threadIdx.x;
    const int b = blockIdx.x / NC, c = blockIdx.x % NC;
    const size_t nb = (size_t)b * NN;
    const int m0 = c * CH;

    int   jv[CH];
    float Fv[CH];
#pragma unroll
    for (int mm = 0; mm < CH; mm++) jv[mm] = perm[nb + m0 + mm];
#pragma unroll
    for (int mm = 0; mm < CH; mm++) Fv[mm] = Fsorted[nb + m0 + mm];

    float hv[CH];
#pragma unroll
    for (int mm = 0; mm < CH; mm++)
        hv[mm] = hw[(nb + jv[mm]) * DD + t];

    float a0 = 0.f, a1 = 0.f;
#pragma unroll
    for (int mm = 0; mm < CH; mm++) {
        const int m = m0 + mm;
        Q0L[(nb + m) * DD + t] = a0;
        Q1L[(nb + m) * DD + t] = a1;
        a0 += hv[mm];
        a1 += Fv[mm] * hv[mm];
    }
    C0[((size_t)b * NC + c) * DD + t] = a0;
    C1[((size_t)b * NC + c) * DD + t] = a1;

    if (t == 0) {
        float p = 0.f;
#pragma unroll
        for (int mm = 0; mm < CH; mm++) {
            FPL[nb + m0 + mm] = p;
            p += Fv[mm];
        }
        CF[(size_t)b * NC + c] = p;
    }
}

// ---------- Kernel 4a: group sums (32 blocks, parallel) ----------
__global__ __launch_bounds__(128) void GraphAttentionalLayer_1168231104632_fixA(
    const float* __restrict__ C0, const float* __restrict__ C1,
    const float* __restrict__ CF,
    float* __restrict__ G0, float* __restrict__ G1, float* __restrict__ GF)
{
    const int t = threadIdx.x;
    const int b = blockIdx.x >> 2, g = blockIdx.x & 3;   // group of 16 chunks
    const int cbase = (int)((size_t)b * NC + g * 16);

    float s0 = 0.f, s1 = 0.f;
#pragma unroll
    for (int q = 0; q < 16; q++) {
        s0 += C0[(size_t)(cbase + q) * DD + t];
        s1 += C1[(size_t)(cbase + q) * DD + t];
    }
    G0[((size_t)b * NG + g) * DD + t] = s0;
    G1[((size_t)b * NG + g) * DD + t] = s1;

    if (t == 0) {
        float p = 0.f;
#pragma unroll
        for (int q = 0; q < 16; q++) p += CF[cbase + q];
        GF[b * NG + g] = p;
    }
}

// ---------- Kernel 4b: per-chunk offsets (520 blocks, parallel) ----------
__global__ __launch_bounds__(128) void GraphAttentionalLayer_1168231104632_fixB(
    const float* __restrict__ C0, const float* __restrict__ C1,
    const float* __restrict__ CF,
    const float* __restrict__ G0, const float* __restrict__ G1,
    const float* __restrict__ GF,
    float* __restrict__ O0, float* __restrict__ O1, float* __restrict__ OF)
{
    const int t = threadIdx.x;
    const int b = blockIdx.x / NO, c = blockIdx.x % NO;   // c in [0, NC]
    const int gc = c >> 4;

    float o0 = 0.f, o1 = 0.f;
    for (int g = 0; g < gc; g++) {
        o0 += G0[((size_t)b * NG + g) * DD + t];
        o1 += G1[((size_t)b * NG + g) * DD + t];
    }
    for (int c2 = gc * 16; c2 < c; c2++) {
        o0 += C0[((size_t)b * NC + c2) * DD + t];
        o1 += C1[((size_t)b * NC + c2) * DD + t];
    }
    O0[((size_t)b * NO + c) * DD + t] = o0;
    O1[((size_t)b * NO + c) * DD + t] = o1;

    if (t == 0) {
        float p = 0.f;
        for (int g = 0; g < gc; g++) p += GF[b * NG + g];
        for (int c2 = gc * 16; c2 < c; c2++) p += CF[(size_t)b * NC + c2];
        OF[(size_t)b * NO + c] = p;
    }
}

// ---------- Kernel 5: output with fused k-search + z (r10 verbatim) ----------
__global__ __launch_bounds__(128) void GraphAttentionalLayer_1168231104632_out(
    const float* __restrict__ Q0L, const float* __restrict__ Q1L,
    const float* __restrict__ O0,  const float* __restrict__ O1,
    const float* __restrict__ Fsorted, const float* __restrict__ FPL,
    const float* __restrict__ OF,  const float* __restrict__ E,
    float* __restrict__ out)
{
    __shared__ int   k_sh;
    __shared__ float e_sh, zi_sh;

    const int t = threadIdx.x;
    const int row = blockIdx.x;
    const int b = row >> 11;
    const size_t nb = (size_t)b * NN;

    if (t == 0) {
        const float Ei = E[row];
        const float thr = 1.0f / Ei;
        int lo = 0, hi = NN;
        while (lo < hi) {
            const int mid = (lo + hi) >> 1;
            if (Fsorted[nb + mid] < thr) lo = mid + 1; else hi = mid;
        }
        const float TF = OF[(size_t)b * NO + NC];
        const float Pk = (lo < NN) ? (OF[(size_t)b * NO + (lo >> 5)] + FPL[nb + lo]) : TF;
        const float z = Ei * (TF - Pk) + (float)lo;
        k_sh = lo; e_sh = Ei; zi_sh = 1.0f / z;
    }
    __syncthreads();

    const int k = k_sh;
    const float Ev = e_sh, zv = zi_sh;
    const float T1 = O1[((size_t)b * NO + NC) * DD + t];

    float num;
    if (k < NN) {
        const int c = k >> 5;
        const float q0 = Q0L[(nb + k) * DD + t] + O0[((size_t)b * NO + c) * DD + t];
        const float q1 = Q1L[(nb + k) * DD + t] + O1[((size_t)b * NO + c) * DD + t];
        num = Ev * (T1 - q1) + q0;
    } else {
        num = O0[((size_t)b * NO + NC) * DD + t];
    }
    out[(size_t)row * DD + t] = relu(num * zv);
}

extern "C" __attribute__((visibility("default")))
void kernel_launch(void* const* d_in, const int* in_sizes, int n_in,
                   void* d_out, int out_size, void* d_ws, size_t ws_size,
                   hipStream_t stream) {
    const float* h = nullptr; const float* W = nullptr; const float* a = nullptr;
    for (int i = 0; i < n_in; i++) {
        if (in_sizes[i] == BB * NN * DD)      h = (const float*)d_in[i];
        else if (in_sizes[i] == DD * DD)      W = (const float*)d_in[i];
        else if (in_sizes[i] == 2 * DD)       a = (const float*)d_in[i];
    }
    if (!h) h = (const float*)d_in[0];
    if (!W) W = (const float*)d_in[1];
    if (!a) a = (const float*)d_in[2];

    float* out = (float*)d_out;
    float* ws = (float*)d_ws;

    float* WT   = ws;                              // 16,384
    float* hw   = WT + DD * DD;                    // 2,097,152
    float* E    = hw + (size_t)BB * NN * DD;       // 16,384
    float* F    = E + BB * NN;                     // 16,384
    float* Fs   = F + BB * NN;                     // 16,384
    float* FPL  = Fs + BB * NN;                    // 16,384
    float* CF   = FPL + BB * NN;                   // 512
    float* OF   = CF + BB * NC;                    // 520
    float* GF   = OF + BB * NO;                    // 32
    int*   perm = (int*)(GF + BB * NG);            // 16,384
    float* Q0L  = (float*)(perm + BB * NN);        // 2,097,152
    float* Q1L  = Q0L + (size_t)BB * NN * DD;      // 2,097,152
    float* C0   = Q1L + (size_t)BB * NN * DD;      // 65,536
    float* C1   = C0 + BB * NC * DD;               // 65,536
    float* G0   = C1 + BB * NC * DD;               // 4,096
    float* G1   = G0 + BB * NG * DD;               // 4,096
    float* O0   = G1 + BB * NG * DD;               // 66,560
    float* O1   = O0 + BB * NO * DD;               // 66,560
    const size_t need = (size_t)((O1 + BB * NO * DD) - ws) * sizeof(float); // ~26.7 MB

    if (ws_size < need || d_ws == nullptr) {
        hipMemsetAsync(d_out, 0x42, (size_t)out_size * sizeof(float), stream);
        return;
    }

    GraphAttentionalLayer_1168231104632_tr<<<(DD * DD) / 256, 256, 0, stream>>>(W, WT);
    GraphAttentionalLayer_1168231104632_kernel<<<BB * (NN / TI), 128, 0, stream>>>(h, WT, a, hw, E, F);
    GraphAttentionalLayer_1168231104632_rank<<<BB * 32, 256, 0, stream>>>(F, Fs, perm);
    GraphAttentionalLayer_1168231104632_scan<<<BB * NC, 128, 0, stream>>>(hw, Fs, perm, Q0L, Q1L, C0, C1, FPL, CF);
    GraphAttentionalLayer_1168231104632_fixA<<<BB * NG, 128, 0, stream>>>(C0, C1, CF, G0, G1, GF);
    GraphAttentionalLayer_1168231104632_fixB<<<BB * NO, 128, 0, stream>>>(C0, C1, CF, G0, G1, GF, O0, O1, OF);
    GraphAttentionalLayer_1168231104632_out<<<BB * NN, 128, 0, stream>>>(Q0L, Q1L, O0, O1, Fs, FPL, OF, E, out);
}

// Round 13
// 112.744 us; speedup vs baseline: 2.3281x; 1.1230x over previous
//
#include <hip/hip_runtime.h>
#include <hip/hip_bf16.h>

#define BB 8
#define NN 2048
#define DD 128
#define TI 32     // i-rows per GEMM block (256 threads)
#define HP 132    // padded row stride for 128-wide LDS tiles
#define CH 32     // scan chunk length
#define NC (NN / CH)   // 64 chunks per batch
#define NO (NC + 1)    // 65 offset rows (incl. grand total)
#define NFIX (BB * NO) // 520 fix blocks inside mid kernel

__device__ __forceinline__ float relu(float x) { return x > 0.f ? x : 0.f; }

// ---------- Kernel 0: WT[d][e] = W[e][d] ----------
__global__ __launch_bounds__(256) void GraphAttentionalLayer_1168231104632_tr(
    const float* __restrict__ W, float* __restrict__ WT)
{
    const int g = blockIdx.x * 256 + threadIdx.x;
    const int d = g >> 7, e = g & 127;
    WT[g] = W[e * DD + d];
}

// ---------- Kernel 1: hw = h@W^T ; E=exp(si), F=exp(sj) ----------
// TI=32 rows per block, 256 threads (thread tile 4x4). Inner loop identical
// to the r9-verified pattern; WT staged once per 32 output rows (2x reuse vs r9).
__global__ __launch_bounds__(256) void GraphAttentionalLayer_1168231104632_kernel(
    const float* __restrict__ h,
    const float* __restrict__ WT,
    const float* __restrict__ a,
    float* __restrict__ hw,
    float* __restrict__ E,
    float* __restrict__ F)
{
    __shared__ float h_s[TI][HP];     // 16.9 KB
    __shared__ float wt_s[32][HP];    // 16.9 KB

    const int tid = threadIdx.x;
    const int t = tid & 127;
    const int hh = tid >> 7;          // 0/1
    const int tx = tid & 31, ty = tid >> 5;   // ty in 0..7
    const int b = blockIdx.x >> 6;
    const int i0 = (blockIdx.x & 63) * TI;
    const size_t base = ((size_t)b * NN + i0) * DD;

    for (int r = hh; r < TI; r += 2)
        h_s[r][t] = h[base + (size_t)r * DD + t];

    const int e0 = tx * 4, r0 = ty * 4;
    float acc[4][4];
#pragma unroll
    for (int i = 0; i < 4; i++)
#pragma unroll
        for (int j = 0; j < 4; j++) acc[i][j] = 0.f;

    for (int dc = 0; dc < DD; dc += 32) {
        __syncthreads();
        for (int rr = hh; rr < 32; rr += 2)
            wt_s[rr][t] = WT[(size_t)(dc + rr) * DD + t];
        __syncthreads();
#pragma unroll 4
        for (int dd = 0; dd < 32; dd++) {
            const float4 wv = *reinterpret_cast<const float4*>(&wt_s[dd][e0]);
            const float w4[4] = {wv.x, wv.y, wv.z, wv.w};
#pragma unroll
            for (int r = 0; r < 4; r++) {
                const float hv = h_s[r0 + r][dc + dd];
#pragma unroll
                for (int e = 0; e < 4; e++) acc[r][e] += hv * w4[e];
            }
        }
    }

#pragma unroll
    for (int r = 0; r < 4; r++) {
        float4 o = make_float4(acc[r][0], acc[r][1], acc[r][2], acc[r][3]);
        *reinterpret_cast<float4*>(&hw[base + (size_t)(r0 + r) * DD + e0]) = o;
    }

    const float4 aiv = *reinterpret_cast<const float4*>(&a[e0]);
    const float4 ajv = *reinterpret_cast<const float4*>(&a[DD + e0]);
    const float ai4[4] = {aiv.x, aiv.y, aiv.z, aiv.w};
    const float aj4[4] = {ajv.x, ajv.y, ajv.z, ajv.w};
#pragma unroll
    for (int r = 0; r < 4; r++) {
        float pi = 0.f, pj = 0.f;
#pragma unroll
        for (int e = 0; e < 4; e++) { pi += acc[r][e] * ai4[e]; pj += acc[r][e] * aj4[e]; }
#pragma unroll
        for (int off = 16; off > 0; off >>= 1) {
            pi += __shfl_down(pi, off, 32);
            pj += __shfl_down(pj, off, 32);
        }
        if (tx == 0) {
            const size_t row = (size_t)b * NN + i0 + r0 + r;
            E[row] = __expf(pi);
            F[row] = __expf(pj);
        }
    }
}

// ---------- Kernel 2: rank-sort, cooperative (r9 verbatim) ----------
__global__ __launch_bounds__(256) void GraphAttentionalLayer_1168231104632_rank(
    const float* __restrict__ F,
    float* __restrict__ Fsorted,
    int* __restrict__ perm)
{
    __shared__ float F_s[NN];
    __shared__ int   part[4][64];

    const int t = threadIdx.x;
    const int b = blockIdx.x >> 5;
    const int j0 = (blockIdx.x & 31) * 64;
    const size_t nb = (size_t)b * NN;

    for (int q = 0; q < NN / 256; q++)
        F_s[q * 256 + t] = F[nb + q * 256 + t];
    __syncthreads();

    const int tj = t & 63, ts = t >> 6;
    const int j = j0 + tj;
    const float fj = F_s[j];
    const int m0 = ts * (NN / 4);
    int cnt = 0;
#pragma unroll 8
    for (int mi = 0; mi < NN / 4; mi++) {
        const int m = m0 + mi;
        const float fm = F_s[m];
        cnt += (fm < fj) | ((fm == fj) & (m < j));
    }
    part[ts][tj] = cnt;
    __syncthreads();
    if (ts == 0) {
        const int r = part[0][tj] + part[1][tj] + part[2][tj] + part[3][tj];
        Fsorted[nb + r] = fj;
        perm[nb + r] = j;
    }
}

// ---------- Kernel 3: chunked scans (r9 body; metadata tail removed) ----------
__global__ __launch_bounds__(128) void GraphAttentionalLayer_1168231104632_scan(
    const float* __restrict__ hw,
    const float* __restrict__ Fsorted,
    const int* __restrict__ perm,
    float* __restrict__ Q0L, float* __restrict__ Q1L,
    float* __restrict__ C0,  float* __restrict__ C1)
{
    const int t = threadIdx.x;
    const int b = blockIdx.x / NC, c = blockIdx.x % NC;
    const size_t nb = (size_t)b * NN;
    const int m0 = c * CH;

    int   jv[CH];
    float Fv[CH];
#pragma unroll
    for (int mm = 0; mm < CH; mm++) jv[mm] = perm[nb + m0 + mm];
#pragma unroll
    for (int mm = 0; mm < CH; mm++) Fv[mm] = Fsorted[nb + m0 + mm];

    float hv[CH];
#pragma unroll
    for (int mm = 0; mm < CH; mm++)
        hv[mm] = hw[(nb + jv[mm]) * DD + t];

    float a0 = 0.f, a1 = 0.f;
#pragma unroll
    for (int mm = 0; mm < CH; mm++) {
        const int m = m0 + mm;
        Q0L[(nb + m) * DD + t] = a0;
        Q1L[(nb + m) * DD + t] = a1;
        a0 += hv[mm];
        a1 += Fv[mm] * hv[mm];
    }
    C0[((size_t)b * NC + c) * DD + t] = a0;
    C1[((size_t)b * NC + c) * DD + t] = a1;
}

// ---------- Kernel 4 (mid): fix offsets + parallel LDS search ----------
// Blocks [0, NFIX): O0/O1 chunk offsets (t<128: O0 col; t>=128: O1 col).
// Blocks [NFIX, NFIX + BB*8): 256 searches each, Fs LDS-resident.
__global__ __launch_bounds__(256) void GraphAttentionalLayer_1168231104632_mid(
    const float* __restrict__ C0, const float* __restrict__ C1,
    const float* __restrict__ Fsorted, const float* __restrict__ E,
    float* __restrict__ O0, float* __restrict__ O1,
    int* __restrict__ kk,  float* __restrict__ zinv)
{
    __shared__ float fs_s[NN];      // 8 KB
    __shared__ float cf_s[NC];
    __shared__ float of_s[NO];

    const int tid = threadIdx.x;

    if (blockIdx.x < NFIX) {
        const int b = blockIdx.x / NO, c = blockIdx.x % NO;   // c in [0, NC]
        const int d = tid & 127;
        const float* C = (tid < 128) ? C0 : C1;
        float*       O = (tid < 128) ? O0 : O1;
        float o = 0.f;
        int c2 = 0;
        for (; c2 + 16 <= c; c2 += 16) {
            float v[16];
#pragma unroll
            for (int q = 0; q < 16; q++)
                v[q] = C[((size_t)b * NC + c2 + q) * DD + d];
#pragma unroll
            for (int q = 0; q < 16; q++) o += v[q];
        }
        for (; c2 < c; c2++)
            o += C[((size_t)b * NC + c2) * DD + d];
        O[((size_t)b * NO + c) * DD + d] = o;
        return;
    }

    // ---- search part ----
    const int sb = blockIdx.x - NFIX;
    const int b = sb >> 3;
    const int i0 = (sb & 7) * 256;
    const size_t nb = (size_t)b * NN;

    for (int q = 0; q < NN / 256; q++)
        fs_s[q * 256 + tid] = Fsorted[nb + q * 256 + tid];
    __syncthreads();

    if (tid < NC) {                       // per-chunk F sums (ascending order)
        float p = 0.f;
        const int m0 = tid * CH;
#pragma unroll
        for (int mm = 0; mm < CH; mm++) p += fs_s[m0 + mm];
        cf_s[tid] = p;
    }
    __syncthreads();
    if (tid < NO) {                       // exclusive prefix of cf (ascending)
        float p = 0.f;
        for (int c2 = 0; c2 < tid; c2++) p += cf_s[c2];
        of_s[tid] = p;                    // of_s[NC] = TF
    }
    __syncthreads();

    const int row = (int)nb + i0 + tid;
    const float Ei = E[row];
    const float thr = 1.0f / Ei;
    int lo = 0, hi = NN;
    while (lo < hi) {
        const int mid = (lo + hi) >> 1;
        if (fs_s[mid] < thr) lo = mid + 1; else hi = mid;
    }
    float fpl = 0.f;
    for (int m = (lo >> 5) << 5; m < lo; m++) fpl += fs_s[m];
    const float TF = of_s[NC];
    const float Pk = of_s[lo >> 5] + fpl;         // lo==NN -> of_s[64]=TF, fpl=0
    const float z = Ei * (TF - Pk) + (float)lo;
    kk[row] = lo;
    zinv[row] = 1.0f / z;
}

// ---------- Kernel 5: output (r9 verbatim: one block per i-row) ----------
__global__ __launch_bounds__(128) void GraphAttentionalLayer_1168231104632_out(
    const float* __restrict__ Q0L, const float* __restrict__ Q1L,
    const float* __restrict__ O0,  const float* __restrict__ O1,
    const int* __restrict__ kk,    const float* __restrict__ zinv,
    const float* __restrict__ E,   float* __restrict__ out)
{
    const int t = threadIdx.x;
    const int row = blockIdx.x;          // 0 .. BB*NN-1
    const int b = row >> 11;
    const size_t nb = (size_t)b * NN;

    const int k = kk[row];               // uniform
    const float Ev = E[row];
    const float zv = zinv[row];
    const float T1 = O1[((size_t)b * NO + NC) * DD + t];

    float num;
    if (k < NN) {
        const int c = k >> 5;
        const float q0 = Q0L[(nb + k) * DD + t] + O0[((size_t)b * NO + c) * DD + t];
        const float q1 = Q1L[(nb + k) * DD + t] + O1[((size_t)b * NO + c) * DD + t];
        num = Ev * (T1 - q1) + q0;
    } else {
        num = O0[((size_t)b * NO + NC) * DD + t];
    }
    out[(size_t)row * DD + t] = relu(num * zv);
}

extern "C" __attribute__((visibility("default")))
void kernel_launch(void* const* d_in, const int* in_sizes, int n_in,
                   void* d_out, int out_size, void* d_ws, size_t ws_size,
                   hipStream_t stream) {
    const float* h = nullptr; const float* W = nullptr; const float* a = nullptr;
    for (int i = 0; i < n_in; i++) {
        if (in_sizes[i] == BB * NN * DD)      h = (const float*)d_in[i];
        else if (in_sizes[i] == DD * DD)      W = (const float*)d_in[i];
        else if (in_sizes[i] == 2 * DD)       a = (const float*)d_in[i];
    }
    if (!h) h = (const float*)d_in[0];
    if (!W) W = (const float*)d_in[1];
    if (!a) a = (const float*)d_in[2];

    float* out = (float*)d_out;
    float* ws = (float*)d_ws;

    float* WT   = ws;                              // 16,384
    float* hw   = WT + DD * DD;                    // 2,097,152
    float* E    = hw + (size_t)BB * NN * DD;       // 16,384
    float* F    = E + BB * NN;                     // 16,384
    float* Fs   = F + BB * NN;                     // 16,384
    float* zinv = Fs + BB * NN;                    // 16,384
    int*   perm = (int*)(zinv + BB * NN);          // 16,384
    int*   kk   = perm + BB * NN;                  // 16,384
    float* Q0L  = (float*)(kk + BB * NN);          // 2,097,152
    float* Q1L  = Q0L + (size_t)BB * NN * DD;      // 2,097,152
    float* C0   = Q1L + (size_t)BB * NN * DD;      // 65,536
    float* C1   = C0 + BB * NC * DD;               // 65,536
    float* O0   = C1 + BB * NC * DD;               // 66,560
    float* O1   = O0 + BB * NO * DD;               // 66,560
    const size_t need = (size_t)((O1 + BB * NO * DD) - ws) * sizeof(float); // ~26.4 MB

    if (ws_size < need || d_ws == nullptr) {
        hipMemsetAsync(d_out, 0x42, (size_t)out_size * sizeof(float), stream);
        return;
    }

    GraphAttentionalLayer_1168231104632_tr<<<(DD * DD) / 256, 256, 0, stream>>>(W, WT);
    GraphAttentionalLayer_1168231104632_kernel<<<BB * (NN / TI), 256, 0, stream>>>(h, WT, a, hw, E, F);
    GraphAttentionalLayer_1168231104632_rank<<<BB * 32, 256, 0, stream>>>(F, Fs, perm);
    GraphAttentionalLayer_1168231104632_scan<<<BB * NC, 128, 0, stream>>>(hw, Fs, perm, Q0L, Q1L, C0, C1);
    GraphAttentionalLayer_1168231104632_mid<<<NFIX + BB * 8, 256, 0, stream>>>(C0, C1, Fs, E, O0, O1, kk, zinv);
    GraphAttentionalLayer_1168231104632_out<<<BB * NN, 128, 0, stream>>>(Q0L, Q1L, O0, O1, kk, zinv, E, out);
}